// Round 11
// baseline (207.916 us; speedup 1.0000x reference)
//
#include <hip/hip_runtime.h>

typedef float f32x16 __attribute__((ext_vector_type(16)));
typedef float f32x4  __attribute__((ext_vector_type(4)));
typedef short s16x8  __attribute__((ext_vector_type(8)));
typedef short s16x4  __attribute__((ext_vector_type(4)));

constexpr int Bn = 2, Tn = 2048, Dn = 768, Hn = 12, DHn = 64;
constexpr int NX = Bn * Tn * Dn;   // 3,145,728
constexpr int NW = Dn * Dn;        // 589,824
constexpr float SC2f = 0.125f * 1.44269504088896f;  // (1/sqrt(64))*log2(e)

__device__ __forceinline__ unsigned short f2bf(float f) {
    union { float f; unsigned int i; } c; c.f = f;
    unsigned int u = c.i;
    u += 0x7fffu + ((u >> 16) & 1u);
    return (unsigned short)(u >> 16);
}
__device__ __forceinline__ unsigned int cvtpk(float lo, float hi) {
    unsigned int r;
    asm("v_cvt_pk_bf16_f32 %0, %1, %2" : "=v"(r) : "v"(lo), "v"(hi));
    return r;
}
__device__ __forceinline__ s16x8 comb(s16x4 lo, s16x4 hi) {
    s16x8 r;
    r[0]=lo[0]; r[1]=lo[1]; r[2]=lo[2]; r[3]=lo[3];
    r[4]=hi[0]; r[5]=hi[1]; r[6]=hi[2]; r[7]=hi[3];
    return r;
}
__device__ __forceinline__ void barrier_lgkm() {
    asm volatile("s_waitcnt lgkmcnt(0)" ::: "memory");
    __builtin_amdgcn_s_barrier();
    asm volatile("" ::: "memory");
}

// ---- f32 -> bf16 one-shot conversion of x, Wq, Wk, Wv into ws ----
__global__ __launch_bounds__(256) void cvt_bf16(
    const float* __restrict__ x,  const float* __restrict__ wq,
    const float* __restrict__ wk, const float* __restrict__ wv,
    unsigned short* __restrict__ out)
{
    const long i8 = ((long)blockIdx.x * 256 + threadIdx.x) * 8;
    const float* src;
    if (i8 < NX)               src = x  + i8;
    else if (i8 < NX + NW)     src = wq + (i8 - NX);
    else if (i8 < NX + 2*NW)   src = wk + (i8 - NX - 2l*NW + NW);
    else                       src = wv + (i8 - NX - 2l*NW);
    f32x4 a = *(const f32x4*)src;
    f32x4 b = *(const f32x4*)(src + 4);
    union { unsigned int u[4]; s16x8 v; } P;
    P.u[0] = cvtpk(a[0], a[1]); P.u[1] = cvtpk(a[2], a[3]);
    P.u[2] = cvtpk(b[0], b[1]); P.u[3] = cvtpk(b[2], b[3]);
    *(s16x8*)(out + i8) = P.v;
}

// ---- LDS-staged QKV projection: 128x128 tile, BK=32, double-buffered ----
__global__ __launch_bounds__(256) void proj_staged(
    const unsigned short* __restrict__ xbf,
    const unsigned short* __restrict__ wbf,   // [3][NW]
    const float* __restrict__ bq, const float* __restrict__ bk,
    const float* __restrict__ bv,
    unsigned short* __restrict__ qo, unsigned short* __restrict__ ko,
    unsigned short* __restrict__ vo)
{
    __shared__ unsigned short lA[2][128 * 40];
    __shared__ unsigned short lB[2][128 * 40];

    const int z = blockIdx.z;
    const bool vt = (z == 2);
    const unsigned short* W = wbf + (size_t)z * NW;
    const float* bias = (z == 0) ? bq : (z == 1) ? bk : bv;
    const int tid = threadIdx.x, lane = tid & 63, wid = tid >> 6;
    const int lq = lane & 31, g = lane >> 5;
    const int mb = vt ? blockIdx.y : blockIdx.x;
    const int nb = vt ? blockIdx.x : blockIdx.y;
    const unsigned short* Am = vt ? W : xbf;
    const unsigned short* Bm = vt ? xbf : W;

    const int srow = tid >> 2, sch = tid & 3;
    const unsigned short* ag0 = Am + (size_t)(mb * 128 +      srow) * Dn + sch * 8;
    const unsigned short* ag1 = Am + (size_t)(mb * 128 + 64 + srow) * Dn + sch * 8;
    const unsigned short* bg0 = Bm + (size_t)(nb * 128 +      srow) * Dn + sch * 8;
    const unsigned short* bg1 = Bm + (size_t)(nb * 128 + 64 + srow) * Dn + sch * 8;
    const int sd0 = srow * 40 + sch * 8;
    const int sd1 = (64 + srow) * 40 + sch * 8;

    f32x16 acc[2][2];
#pragma unroll
    for (int am = 0; am < 2; ++am)
#pragma unroll
        for (int bn = 0; bn < 2; ++bn)
#pragma unroll
            for (int i = 0; i < 16; ++i) acc[am][bn][i] = 0.f;

    {
        s16x8 a0 = *(const s16x8*)ag0, a1 = *(const s16x8*)ag1;
        s16x8 b0 = *(const s16x8*)bg0, b1 = *(const s16x8*)bg1;
        *(s16x8*)&lA[0][sd0] = a0; *(s16x8*)&lA[0][sd1] = a1;
        *(s16x8*)&lB[0][sd0] = b0; *(s16x8*)&lB[0][sd1] = b1;
    }
    const int ar = (wid & 1) * 64 + lq;
    const int br = (wid >> 1) * 64 + lq;

    for (int kt = 0; kt < 24; ++kt) {
        const int cur = kt & 1;
        s16x8 a0, a1, b0, b1;
        if (kt < 23) {
            a0 = *(const s16x8*)(ag0 + (kt + 1) * 32);
            a1 = *(const s16x8*)(ag1 + (kt + 1) * 32);
            b0 = *(const s16x8*)(bg0 + (kt + 1) * 32);
            b1 = *(const s16x8*)(bg1 + (kt + 1) * 32);
        }
        barrier_lgkm();
        s16x8 afr[2][2], bfr[2][2];
#pragma unroll
        for (int am = 0; am < 2; ++am)
#pragma unroll
            for (int kc = 0; kc < 2; ++kc)
                afr[am][kc] = *(const s16x8*)&lA[cur][(ar + am * 32) * 40 + (2 * kc + g) * 8];
#pragma unroll
        for (int bn = 0; bn < 2; ++bn)
#pragma unroll
            for (int kc = 0; kc < 2; ++kc)
                bfr[bn][kc] = *(const s16x8*)&lB[cur][(br + bn * 32) * 40 + (2 * kc + g) * 8];
#pragma unroll
        for (int kc = 0; kc < 2; ++kc)
#pragma unroll
            for (int am = 0; am < 2; ++am)
#pragma unroll
                for (int bn = 0; bn < 2; ++bn)
                    acc[am][bn] = __builtin_amdgcn_mfma_f32_32x32x16_bf16(
                        afr[am][kc], bfr[bn][kc], acc[am][bn], 0, 0, 0);
        if (kt < 23) {
            *(s16x8*)&lA[cur ^ 1][sd0] = a0; *(s16x8*)&lA[cur ^ 1][sd1] = a1;
            *(s16x8*)&lB[cur ^ 1][sd0] = b0; *(s16x8*)&lB[cur ^ 1][sd1] = b1;
        }
    }

    if (!vt) {
        unsigned short* out = (z == 0) ? qo : ko;
        const float scale = (z == 0) ? SC2f : 1.f;
#pragma unroll
        for (int bn = 0; bn < 2; ++bn) {
            const int e = nb * 128 + (wid >> 1) * 64 + bn * 32 + lq;
            const float bvl = bias[e];
            const int h = e >> 6, dh = e & 63;
#pragma unroll
            for (int am = 0; am < 2; ++am)
#pragma unroll
                for (int r = 0; r < 16; ++r) {
                    const int t = mb * 128 + (wid & 1) * 64 + am * 32 + ((r & 3) + 8 * (r >> 2) + 4 * g);
                    const int b = t >> 11, tl = t & (Tn - 1);
                    out[((size_t)(b * Hn + h) * Tn + tl) * DHn + dh] = f2bf((acc[am][bn][r] + bvl) * scale);
                }
        }
    } else {
#pragma unroll
        for (int am = 0; am < 2; ++am)
#pragma unroll
            for (int r = 0; r < 16; ++r) {
                const int e = mb * 128 + (wid & 1) * 64 + am * 32 + ((r & 3) + 8 * (r >> 2) + 4 * g);
                const float bvl = bias[e];
                const int h = e >> 6, dh = e & 63;
#pragma unroll
                for (int bn = 0; bn < 2; ++bn) {
                    const int t = nb * 128 + (wid >> 1) * 64 + bn * 32 + lq;
                    const int b = t >> 11, tl = t & (Tn - 1);
                    vo[((size_t)(b * Hn + h) * DHn + dh) * Tn + tl] = f2bf(acc[am][bn][r] + bvl);
                }
            }
    }
}

// Shared decode for lsum/attn: 768 blocks = 24 heads x 32 strip-pairs,
// XCD-chunked (3 heads/XCD). Wave = (strip in {u,63-u}) x (k-chunk).
#define PAIR_DECODE()                                                   \
    const int tid = threadIdx.x, lane = tid & 63, wid = tid >> 6;       \
    const int lq = lane & 31, g = lane >> 5;                            \
    const int n2 = ((int)blockIdx.x & 7) * 96 + ((int)blockIdx.x >> 3); \
    const int bh = n2 >> 5;                                             \
    const int u  = n2 & 31;                                             \
    const int s  = (wid & 2) ? (63 - u) : u;                            \
    const int cc = wid & 1;                                             \
    const int qbase = s * 32;                                           \
    const int h2 = (s + 1) >> 1;                                        \
    const int k0 = cc ? h2 : 0;                                         \
    const int kend = cc ? s : h2;   /* maskless range; cc owns diag s */

// ---- lsum: l[bh][t] = sum_k exp2(q.k), balanced pairs, no atomics ----
__global__ __launch_bounds__(256) void lsum_kernel(
    const unsigned short* __restrict__ Q,   // pre-scaled by SC2
    const unsigned short* __restrict__ K,
    float* __restrict__ lsum)               // [BH][T]
{
    __shared__ float pls[4][32];
    PAIR_DECODE();
    const unsigned short* Qb = Q + ((size_t)bh * Tn + qbase) * DHn;
    const unsigned short* Kb = K + (size_t)bh * Tn * DHn;

    s16x8 qf[4];
#pragma unroll
    for (int c = 0; c < 4; ++c)
        qf[c] = *(const s16x8*)(Qb + lq * DHn + c * 16 + g * 8);

    float ls = 0.f;
    for (int kt = k0; kt < kend; ++kt) {
        const unsigned short* krow = Kb + (size_t)(kt * 32 + lq) * DHn + g * 8;
        f32x16 acc;
#pragma unroll
        for (int i = 0; i < 16; ++i) acc[i] = 0.f;
#pragma unroll
        for (int c = 0; c < 4; ++c)
            acc = __builtin_amdgcn_mfma_f32_32x32x16_bf16(
                *(const s16x8*)(krow + c * 16), qf[c], acc, 0, 0, 0);
#pragma unroll
        for (int r = 0; r < 16; ++r) ls += exp2f(acc[r]);
    }
    if (cc) {  // diagonal tile s, causal-masked
        const unsigned short* krow = Kb + (size_t)(s * 32 + lq) * DHn + g * 8;
        f32x16 acc;
#pragma unroll
        for (int i = 0; i < 16; ++i) acc[i] = 0.f;
#pragma unroll
        for (int c = 0; c < 4; ++c)
            acc = __builtin_amdgcn_mfma_f32_32x32x16_bf16(
                *(const s16x8*)(krow + c * 16), qf[c], acc, 0, 0, 0);
#pragma unroll
        for (int r = 0; r < 16; ++r) {
            const int koff = (r & 3) + 8 * (r >> 2) + 4 * g;
            ls += (koff <= lq) ? exp2f(acc[r]) : 0.f;
        }
    }
    ls += __shfl_xor(ls, 32);
    if (g == 0) pls[wid][lq] = ls;
    __syncthreads();
    if (!cc && g == 0)
        lsum[(size_t)bh * Tn + qbase + lq] = pls[wid][lq] + pls[wid + 1][lq];
}

// ---- main attention: SINGLE QK pass; P -> transposed full-line L2 stores
// + PV; balanced pairs; O combined across k-chunks via PT overlay ----
__global__ __launch_bounds__(256) void attn_main(
    const unsigned short* __restrict__ Q,   // [BH][T][Dh], pre-scaled
    const unsigned short* __restrict__ K,   // [BH][T][Dh]
    const unsigned short* __restrict__ Vt,  // [BH][Dh][T]
    const float* __restrict__ lsum,         // [BH][T]
    float* __restrict__ heads,              // [B][T][H][Dh]
    float* __restrict__ attn)               // [BH][T][T]
{
    __shared__ float pt[4096];              // 4 waves x 4KB; overlaid O-combine
    PAIR_DECODE();
    const unsigned short* Qb = Q  + ((size_t)bh * Tn + qbase) * DHn;
    const unsigned short* Kb = K  + (size_t)bh * Tn * DHn;
    const unsigned short* Vb = Vt + (size_t)bh * DHn * Tn;
    const size_t abase = ((size_t)bh * Tn + qbase) * Tn;
    const float rl = 1.f / lsum[(size_t)bh * Tn + qbase + lq];

    s16x8 qf[4];
#pragma unroll
    for (int c = 0; c < 4; ++c)
        qf[c] = *(const s16x8*)(Qb + lq * DHn + c * 16 + g * 8);

    f32x16 o0, o1;
#pragma unroll
    for (int i = 0; i < 16; ++i) { o0[i] = 0.f; o1[i] = 0.f; }

    float* PT = pt + wid * 1024;
    const int rq = lane >> 3;
    const int rk = (lane & 7) * 4;
    const int rcol = rk ^ (rq << 2);

    auto tile = [&](int kt, bool diag) {
        const unsigned short* krow = Kb + (size_t)(kt * 32 + lq) * DHn + g * 8;
        f32x16 acc;
#pragma unroll
        for (int i = 0; i < 16; ++i) acc[i] = 0.f;
#pragma unroll
        for (int c = 0; c < 4; ++c)
            acc = __builtin_amdgcn_mfma_f32_32x32x16_bf16(
                *(const s16x8*)(krow + c * 16), qf[c], acc, 0, 0, 0);
        float pv[16];
#pragma unroll
        for (int r = 0; r < 16; ++r) {
            const int koff = (r & 3) + 8 * (r >> 2) + 4 * g;
            float e = exp2f(acc[r]) * rl;
            pv[r] = (diag && koff > lq) ? 0.f : e;
        }
        // per-wave 32x32 transpose -> 8-full-line stores (via L2)
#pragma unroll
        for (int a = 0; a < 4; ++a) {
            const int c0 = (4 * g + 8 * a) ^ ((lq & 7) << 2);
            f32x4 w;
            w[0]=pv[4*a+0]; w[1]=pv[4*a+1]; w[2]=pv[4*a+2]; w[3]=pv[4*a+3];
            *(f32x4*)&PT[lq * 32 + c0] = w;
        }
        asm volatile("s_waitcnt lgkmcnt(0)" ::: "memory");
#pragma unroll
        for (int jj = 0; jj < 4; ++jj) {
            const int q = 8 * jj + rq;
            f32x4 w = *(const f32x4*)&PT[q * 32 + rcol];
            *(f32x4*)(attn + abase + (size_t)q * Tn + kt * 32 + rk) = w;
        }
        // PV: P (bf16) via cvt_pk; V^T fragments with matching k-bijection
        union { unsigned int uu[4]; s16x8 v; } P0, P1;
        P0.uu[0]=cvtpk(pv[0],pv[1]);   P0.uu[1]=cvtpk(pv[2],pv[3]);
        P0.uu[2]=cvtpk(pv[4],pv[5]);   P0.uu[3]=cvtpk(pv[6],pv[7]);
        P1.uu[0]=cvtpk(pv[8],pv[9]);   P1.uu[1]=cvtpk(pv[10],pv[11]);
        P1.uu[2]=cvtpk(pv[12],pv[13]); P1.uu[3]=cvtpk(pv[14],pv[15]);
        const unsigned short* vr0 = Vb + (size_t)lq * Tn + kt * 32;
        const unsigned short* vr1 = Vb + (size_t)(32 + lq) * Tn + kt * 32;
#pragma unroll
        for (int c2 = 0; c2 < 2; ++c2) {
            const s16x8 pa = c2 ? P1.v : P0.v;
            s16x4 lo0 = *(const s16x4*)(vr0 + c2 * 16 + 4 * g);
            s16x4 hi0 = *(const s16x4*)(vr0 + c2 * 16 + 8 + 4 * g);
            o0 = __builtin_amdgcn_mfma_f32_32x32x16_bf16(pa, comb(lo0, hi0), o0, 0, 0, 0);
            s16x4 lo1 = *(const s16x4*)(vr1 + c2 * 16 + 4 * g);
            s16x4 hi1 = *(const s16x4*)(vr1 + c2 * 16 + 8 + 4 * g);
            o1 = __builtin_amdgcn_mfma_f32_32x32x16_bf16(pa, comb(lo1, hi1), o1, 0, 0, 0);
        }
    };

    for (int kt = k0; kt < kend; ++kt) tile(kt, false);
    if (cc) tile(s, true);

    // ---- combine the two k-chunks' O via PT overlay ----
    __syncthreads();
    if (cc) {   // waves 1,3 -> slot (wid>>1)
#pragma unroll
        for (int r = 0; r < 16; ++r) {
            const int tr = (r & 3) + 8 * (r >> 2) + 4 * g;
            pt[(wid >> 1) * 2048 + tr * 64 + lq]      = o0[r];
            pt[(wid >> 1) * 2048 + tr * 64 + 32 + lq] = o1[r];
        }
    }
    __syncthreads();
    if (!cc) {
        const int b = bh / Hn, hh = bh % Hn;
        const int slot = (wid >> 1) * 2048;
#pragma unroll
        for (int r = 0; r < 16; ++r) {
            const int tr = (r & 3) + 8 * (r >> 2) + 4 * g;
            float* base = heads + ((size_t)(b * Tn + (qbase + tr))) * Dn + hh * DHn;
            base[lq]      = o0[r] + pt[slot + tr * 64 + lq];
            base[32 + lq] = o1[r] + pt[slot + tr * 64 + 32 + lq];
        }
    }

    // ---- pooled zero-fill of both strips' strictly-upper tiles ----
    {
        f32x4 z; z[0]=0.f; z[1]=0.f; z[2]=0.f; z[3]=0.f;
        const int nzu = 63 - u;   // upper tiles of strip u; strip 63-u has u
        for (int j = wid; j < 63; j += 4) {
            int zs, zkt;
            if (j < nzu) { zs = u;      zkt = u + 1 + j; }
            else         { zs = 63 - u; zkt = (64 - u) + (j - nzu); }
            float* rp = attn + ((size_t)bh * Tn + zs * 32 + rq) * Tn;
#pragma unroll
            for (int a = 0; a < 4; ++a)
                *(f32x4*)(rp + (size_t)(8 * a) * Tn + zkt * 32 + rk) = z;
        }
    }
}

extern "C" void kernel_launch(void* const* d_in, const int* in_sizes, int n_in,
                              void* d_out, int out_size, void* d_ws, size_t ws_size,
                              hipStream_t stream) {
    (void)in_sizes; (void)n_in; (void)out_size; (void)ws_size;
    const float* x  = (const float*)d_in[0];
    const float* Wq = (const float*)d_in[1];
    const float* bq = (const float*)d_in[2];
    const float* Wk = (const float*)d_in[3];
    const float* bk = (const float*)d_in[4];
    const float* Wv = (const float*)d_in[5];
    const float* bv = (const float*)d_in[6];
    // d_in[7] = attn_mask: structurally causal, handled in-kernel.

    float* heads = (float*)d_out;
    float* attn  = heads + (size_t)Bn * Tn * Dn;

    unsigned short* xbf  = (unsigned short*)d_ws;   // [NX] then [3][NW] weights
    unsigned short* qws  = xbf + NX + 3 * (size_t)NW;
    unsigned short* kws  = qws + NX;
    unsigned short* vtws = kws + NX;
    float* lsum = (float*)(vtws + NX);              // [BH][T]

    cvt_bf16<<<(NX + 3 * NW) / (256 * 8), 256, 0, stream>>>(x, Wq, Wk, Wv, xbf);
    proj_staged<<<dim3(32, 6, 3), 256, 0, stream>>>(xbf, xbf + NX, bq, bk, bv,
                                                    qws, kws, vtws);
    lsum_kernel<<<768, 256, 0, stream>>>(qws, kws, lsum);
    attn_main<<<768, 256, 0, stream>>>(qws, kws, vtws, lsum, heads, attn);
}

// Round 12
// 174.508 us; speedup vs baseline: 1.1914x; 1.1914x over previous
//
#include <hip/hip_runtime.h>

typedef float f32x16 __attribute__((ext_vector_type(16)));
typedef float f32x4  __attribute__((ext_vector_type(4)));
typedef short s16x8  __attribute__((ext_vector_type(8)));
typedef short s16x4  __attribute__((ext_vector_type(4)));

constexpr int Bn = 2, Tn = 2048, Dn = 768, Hn = 12, DHn = 64;
constexpr int NX = Bn * Tn * Dn;   // 3,145,728
constexpr int NW = Dn * Dn;        // 589,824
constexpr float SC2f = 0.125f * 1.44269504088896f;  // (1/sqrt(64))*log2(e)

__device__ __forceinline__ unsigned short f2bf(float f) {
    union { float f; unsigned int i; } c; c.f = f;
    unsigned int u = c.i;
    u += 0x7fffu + ((u >> 16) & 1u);
    return (unsigned short)(u >> 16);
}
__device__ __forceinline__ unsigned int cvtpk(float lo, float hi) {
    unsigned int r;
    asm("v_cvt_pk_bf16_f32 %0, %1, %2" : "=v"(r) : "v"(lo), "v"(hi));
    return r;
}
__device__ __forceinline__ s16x8 comb(s16x4 lo, s16x4 hi) {
    s16x8 r;
    r[0]=lo[0]; r[1]=lo[1]; r[2]=lo[2]; r[3]=lo[3];
    r[4]=hi[0]; r[5]=hi[1]; r[6]=hi[2]; r[7]=hi[3];
    return r;
}
__device__ __forceinline__ void barrier_lgkm() {
    asm volatile("s_waitcnt lgkmcnt(0)" ::: "memory");
    __builtin_amdgcn_s_barrier();
    asm volatile("" ::: "memory");
}

// ---- f32 -> bf16 one-shot conversion of x, Wq, Wk, Wv into ws ----
__global__ __launch_bounds__(256) void cvt_bf16(
    const float* __restrict__ x,  const float* __restrict__ wq,
    const float* __restrict__ wk, const float* __restrict__ wv,
    unsigned short* __restrict__ out)
{
    const long i8 = ((long)blockIdx.x * 256 + threadIdx.x) * 8;
    const float* src;
    if (i8 < NX)               src = x  + i8;
    else if (i8 < NX + NW)     src = wq + (i8 - NX);
    else if (i8 < NX + 2*NW)   src = wk + (i8 - NX - 2l*NW + NW);
    else                       src = wv + (i8 - NX - 2l*NW);
    f32x4 a = *(const f32x4*)src;
    f32x4 b = *(const f32x4*)(src + 4);
    union { unsigned int u[4]; s16x8 v; } P;
    P.u[0] = cvtpk(a[0], a[1]); P.u[1] = cvtpk(a[2], a[3]);
    P.u[2] = cvtpk(b[0], b[1]); P.u[3] = cvtpk(b[2], b[3]);
    *(s16x8*)(out + i8) = P.v;
}

// ---- LDS-staged QKV projection: 128x128 tile, BK=32, double-buffered ----
__global__ __launch_bounds__(256) void proj_staged(
    const unsigned short* __restrict__ xbf,
    const unsigned short* __restrict__ wbf,   // [3][NW]
    const float* __restrict__ bq, const float* __restrict__ bk,
    const float* __restrict__ bv,
    unsigned short* __restrict__ qo, unsigned short* __restrict__ ko,
    unsigned short* __restrict__ vo)
{
    __shared__ unsigned short lA[2][128 * 40];
    __shared__ unsigned short lB[2][128 * 40];

    const int z = blockIdx.z;
    const bool vt = (z == 2);
    const unsigned short* W = wbf + (size_t)z * NW;
    const float* bias = (z == 0) ? bq : (z == 1) ? bk : bv;
    const int tid = threadIdx.x, lane = tid & 63, wid = tid >> 6;
    const int lq = lane & 31, g = lane >> 5;
    const int mb = vt ? blockIdx.y : blockIdx.x;
    const int nb = vt ? blockIdx.x : blockIdx.y;
    const unsigned short* Am = vt ? W : xbf;
    const unsigned short* Bm = vt ? xbf : W;

    const int srow = tid >> 2, sch = tid & 3;
    const unsigned short* ag0 = Am + (size_t)(mb * 128 +      srow) * Dn + sch * 8;
    const unsigned short* ag1 = Am + (size_t)(mb * 128 + 64 + srow) * Dn + sch * 8;
    const unsigned short* bg0 = Bm + (size_t)(nb * 128 +      srow) * Dn + sch * 8;
    const unsigned short* bg1 = Bm + (size_t)(nb * 128 + 64 + srow) * Dn + sch * 8;
    const int sd0 = srow * 40 + sch * 8;
    const int sd1 = (64 + srow) * 40 + sch * 8;

    f32x16 acc[2][2];
#pragma unroll
    for (int am = 0; am < 2; ++am)
#pragma unroll
        for (int bn = 0; bn < 2; ++bn)
#pragma unroll
            for (int i = 0; i < 16; ++i) acc[am][bn][i] = 0.f;

    {
        s16x8 a0 = *(const s16x8*)ag0, a1 = *(const s16x8*)ag1;
        s16x8 b0 = *(const s16x8*)bg0, b1 = *(const s16x8*)bg1;
        *(s16x8*)&lA[0][sd0] = a0; *(s16x8*)&lA[0][sd1] = a1;
        *(s16x8*)&lB[0][sd0] = b0; *(s16x8*)&lB[0][sd1] = b1;
    }
    const int ar = (wid & 1) * 64 + lq;
    const int br = (wid >> 1) * 64 + lq;

    for (int kt = 0; kt < 24; ++kt) {
        const int cur = kt & 1;
        s16x8 a0, a1, b0, b1;
        if (kt < 23) {
            a0 = *(const s16x8*)(ag0 + (kt + 1) * 32);
            a1 = *(const s16x8*)(ag1 + (kt + 1) * 32);
            b0 = *(const s16x8*)(bg0 + (kt + 1) * 32);
            b1 = *(const s16x8*)(bg1 + (kt + 1) * 32);
        }
        barrier_lgkm();
        s16x8 afr[2][2], bfr[2][2];
#pragma unroll
        for (int am = 0; am < 2; ++am)
#pragma unroll
            for (int kc = 0; kc < 2; ++kc)
                afr[am][kc] = *(const s16x8*)&lA[cur][(ar + am * 32) * 40 + (2 * kc + g) * 8];
#pragma unroll
        for (int bn = 0; bn < 2; ++bn)
#pragma unroll
            for (int kc = 0; kc < 2; ++kc)
                bfr[bn][kc] = *(const s16x8*)&lB[cur][(br + bn * 32) * 40 + (2 * kc + g) * 8];
#pragma unroll
        for (int kc = 0; kc < 2; ++kc)
#pragma unroll
            for (int am = 0; am < 2; ++am)
#pragma unroll
                for (int bn = 0; bn < 2; ++bn)
                    acc[am][bn] = __builtin_amdgcn_mfma_f32_32x32x16_bf16(
                        afr[am][kc], bfr[bn][kc], acc[am][bn], 0, 0, 0);
        if (kt < 23) {
            *(s16x8*)&lA[cur ^ 1][sd0] = a0; *(s16x8*)&lA[cur ^ 1][sd1] = a1;
            *(s16x8*)&lB[cur ^ 1][sd0] = b0; *(s16x8*)&lB[cur ^ 1][sd1] = b1;
        }
    }

    if (!vt) {
        unsigned short* out = (z == 0) ? qo : ko;
        const float scale = (z == 0) ? SC2f : 1.f;
#pragma unroll
        for (int bn = 0; bn < 2; ++bn) {
            const int e = nb * 128 + (wid >> 1) * 64 + bn * 32 + lq;
            const float bvl = bias[e];
            const int h = e >> 6, dh = e & 63;
#pragma unroll
            for (int am = 0; am < 2; ++am)
#pragma unroll
                for (int r = 0; r < 16; ++r) {
                    const int t = mb * 128 + (wid & 1) * 64 + am * 32 + ((r & 3) + 8 * (r >> 2) + 4 * g);
                    const int b = t >> 11, tl = t & (Tn - 1);
                    out[((size_t)(b * Hn + h) * Tn + tl) * DHn + dh] = f2bf((acc[am][bn][r] + bvl) * scale);
                }
        }
    } else {
#pragma unroll
        for (int am = 0; am < 2; ++am)
#pragma unroll
            for (int r = 0; r < 16; ++r) {
                const int e = mb * 128 + (wid & 1) * 64 + am * 32 + ((r & 3) + 8 * (r >> 2) + 4 * g);
                const float bvl = bias[e];
                const int h = e >> 6, dh = e & 63;
#pragma unroll
                for (int bn = 0; bn < 2; ++bn) {
                    const int t = nb * 128 + (wid >> 1) * 64 + bn * 32 + lq;
                    const int b = t >> 11, tl = t & (Tn - 1);
                    vo[((size_t)(b * Hn + h) * DHn + dh) * Tn + tl] = f2bf(acc[am][bn][r] + bvl);
                }
            }
    }
}

// lsum decode: 768 blocks = 24 heads x 32 strip-pairs, XCD-chunked.
#define PAIR_DECODE()                                                   \
    const int tid = threadIdx.x, lane = tid & 63, wid = tid >> 6;       \
    const int lq = lane & 31, g = lane >> 5;                            \
    const int n2 = ((int)blockIdx.x & 7) * 96 + ((int)blockIdx.x >> 3); \
    const int bh = n2 >> 5;                                             \
    const int u  = n2 & 31;                                             \
    const int s  = (wid & 2) ? (63 - u) : u;                            \
    const int cc = wid & 1;                                             \
    const int qbase = s * 32;                                           \
    const int h2 = (s + 1) >> 1;                                        \
    const int k0 = cc ? h2 : 0;                                         \
    const int kend = cc ? s : h2;   /* maskless range; cc owns diag s */

// ---- lsum: l[bh][t] = sum_k exp2(q.k), balanced pairs, no atomics ----
__global__ __launch_bounds__(256) void lsum_kernel(
    const unsigned short* __restrict__ Q,   // pre-scaled by SC2
    const unsigned short* __restrict__ K,
    float* __restrict__ lsum)               // [BH][T]
{
    __shared__ float pls[4][32];
    PAIR_DECODE();
    const unsigned short* Qb = Q + ((size_t)bh * Tn + qbase) * DHn;
    const unsigned short* Kb = K + (size_t)bh * Tn * DHn;

    s16x8 qf[4];
#pragma unroll
    for (int c = 0; c < 4; ++c)
        qf[c] = *(const s16x8*)(Qb + lq * DHn + c * 16 + g * 8);

    float ls = 0.f;
    for (int kt = k0; kt < kend; ++kt) {
        const unsigned short* krow = Kb + (size_t)(kt * 32 + lq) * DHn + g * 8;
        f32x16 acc;
#pragma unroll
        for (int i = 0; i < 16; ++i) acc[i] = 0.f;
#pragma unroll
        for (int c = 0; c < 4; ++c)
            acc = __builtin_amdgcn_mfma_f32_32x32x16_bf16(
                *(const s16x8*)(krow + c * 16), qf[c], acc, 0, 0, 0);
#pragma unroll
        for (int r = 0; r < 16; ++r) ls += exp2f(acc[r]);
    }
    if (cc) {  // diagonal tile s, causal-masked
        const unsigned short* krow = Kb + (size_t)(s * 32 + lq) * DHn + g * 8;
        f32x16 acc;
#pragma unroll
        for (int i = 0; i < 16; ++i) acc[i] = 0.f;
#pragma unroll
        for (int c = 0; c < 4; ++c)
            acc = __builtin_amdgcn_mfma_f32_32x32x16_bf16(
                *(const s16x8*)(krow + c * 16), qf[c], acc, 0, 0, 0);
#pragma unroll
        for (int r = 0; r < 16; ++r) {
            const int koff = (r & 3) + 8 * (r >> 2) + 4 * g;
            ls += (koff <= lq) ? exp2f(acc[r]) : 0.f;
        }
    }
    ls += __shfl_xor(ls, 32);
    if (g == 0) pls[wid][lq] = ls;
    __syncthreads();
    if (!cc && g == 0)
        lsum[(size_t)bh * Tn + qbase + lq] = pls[wid][lq] + pls[wid + 1][lq];
}

// ---- main attention: panel-buffered row-contiguous writes ----
// Block = one 32-row strip (1536 blocks, longest-first per XCD), 4 waves
// = kt stride-4. P tiles -> 32x256 LDS panel (XOR-swizzled); per panel the
// block flushes 32 rows as 1KB-contiguous NT stores (sequential per row
// across panels -> HBM page locality). Causal zero region rides the same
// path (slots zeroed on diag crossing). PV per-wave; O combined via LDS.
__global__ __launch_bounds__(256) void attn_main(
    const unsigned short* __restrict__ Q,   // [BH][T][Dh], pre-scaled
    const unsigned short* __restrict__ K,   // [BH][T][Dh]
    const unsigned short* __restrict__ Vt,  // [BH][Dh][T]
    const float* __restrict__ lsum,         // [BH][T]
    float* __restrict__ heads,              // [B][T][H][Dh]
    float* __restrict__ attn)               // [BH][T][T]
{
    __shared__ float P[32 * 256];           // 32KB panel; O-combine overlay

    const int tid = threadIdx.x, lane = tid & 63, wid = tid >> 6;
    const int lq = lane & 31, g = lane >> 5;
    // 1536 blocks: XCD k owns heads [3k,3k+3); longest strips first.
    const int n2 = ((int)blockIdx.x & 7) * 192 + ((int)blockIdx.x >> 3);
    const int bh = n2 >> 6;
    const int s  = 63 - (n2 & 63);
    const int qbase = s * 32;

    const unsigned short* Qb = Q  + ((size_t)bh * Tn + qbase) * DHn;
    const unsigned short* Kb = K  + (size_t)bh * Tn * DHn;
    const unsigned short* Vb = Vt + (size_t)bh * DHn * Tn;
    const float rl = 1.f / lsum[(size_t)bh * Tn + qbase + lq];
    const int swz = (lq & 7) << 2;

    s16x8 qf[4];
#pragma unroll
    for (int c = 0; c < 4; ++c)
        qf[c] = *(const s16x8*)(Qb + lq * DHn + c * 16 + g * 8);

    f32x16 o0, o1;
#pragma unroll
    for (int i = 0; i < 16; ++i) { o0[i] = 0.f; o1[i] = 0.f; }

    for (int p = 0; p < 8; ++p) {
#pragma unroll
        for (int j = 0; j < 2; ++j) {
            const int kt = p * 8 + wid + 4 * j;
            const int slot = (kt & 7) * 32;
            if (kt <= s) {
                const unsigned short* krow = Kb + (size_t)(kt * 32 + lq) * DHn + g * 8;
                f32x16 acc;
#pragma unroll
                for (int i = 0; i < 16; ++i) acc[i] = 0.f;
#pragma unroll
                for (int c = 0; c < 4; ++c)
                    acc = __builtin_amdgcn_mfma_f32_32x32x16_bf16(
                        *(const s16x8*)(krow + c * 16), qf[c], acc, 0, 0, 0);
                const bool diag = (kt == s);
                float pv[16];
#pragma unroll
                for (int r = 0; r < 16; ++r) {
                    const int koff = (r & 3) + 8 * (r >> 2) + 4 * g;
                    float e = exp2f(acc[r]) * rl;
                    pv[r] = (diag && koff > lq) ? 0.f : e;
                }
                // P-tile into panel (row lq, swizzled cols)
#pragma unroll
                for (int a = 0; a < 4; ++a) {
                    f32x4 w;
                    w[0]=pv[4*a+0]; w[1]=pv[4*a+1]; w[2]=pv[4*a+2]; w[3]=pv[4*a+3];
                    *(f32x4*)&P[lq * 256 + slot + ((4 * g + 8 * a) ^ swz)] = w;
                }
                // PV: P (bf16) via cvt_pk; V^T fragments, matching k-bijection
                union { unsigned int uu[4]; s16x8 v; } P0, P1;
                P0.uu[0]=cvtpk(pv[0],pv[1]);   P0.uu[1]=cvtpk(pv[2],pv[3]);
                P0.uu[2]=cvtpk(pv[4],pv[5]);   P0.uu[3]=cvtpk(pv[6],pv[7]);
                P1.uu[0]=cvtpk(pv[8],pv[9]);   P1.uu[1]=cvtpk(pv[10],pv[11]);
                P1.uu[2]=cvtpk(pv[12],pv[13]); P1.uu[3]=cvtpk(pv[14],pv[15]);
                const unsigned short* vr0 = Vb + (size_t)lq * Tn + kt * 32;
                const unsigned short* vr1 = Vb + (size_t)(32 + lq) * Tn + kt * 32;
#pragma unroll
                for (int c2 = 0; c2 < 2; ++c2) {
                    const s16x8 pa = c2 ? P1.v : P0.v;
                    s16x4 lo0 = *(const s16x4*)(vr0 + c2 * 16 + 4 * g);
                    s16x4 hi0 = *(const s16x4*)(vr0 + c2 * 16 + 8 + 4 * g);
                    o0 = __builtin_amdgcn_mfma_f32_32x32x16_bf16(pa, comb(lo0, hi0), o0, 0, 0, 0);
                    s16x4 lo1 = *(const s16x4*)(vr1 + c2 * 16 + 4 * g);
                    s16x4 hi1 = *(const s16x4*)(vr1 + c2 * 16 + 8 + 4 * g);
                    o1 = __builtin_amdgcn_mfma_f32_32x32x16_bf16(pa, comb(lo1, hi1), o1, 0, 0, 0);
                }
            } else if (kt < 8 || kt - 8 <= s) {
                // first time this slot goes past the diagonal: zero it once
                f32x4 z; z[0]=0.f; z[1]=0.f; z[2]=0.f; z[3]=0.f;
#pragma unroll
                for (int a = 0; a < 4; ++a)
                    *(f32x4*)&P[lq * 256 + slot + ((4 * g + 8 * a) ^ swz)] = z;
            }
        }
        barrier_lgkm();
        // flush panel p: wave wid writes rows wid*8..wid*8+7, 1KB/row NT
#pragma unroll
        for (int j2 = 0; j2 < 8; ++j2) {
            const int row = wid * 8 + j2;
            f32x4 w = *(const f32x4*)&P[row * 256 + ((lane * 4) ^ ((row & 7) << 2))];
            __builtin_nontemporal_store(w,
                (f32x4*)(attn + ((size_t)bh * Tn + qbase + row) * Tn + p * 256 + lane * 4));
        }
        barrier_lgkm();
    }

    // ---- combine 4 waves' O via panel overlay; wave 0 writes heads ----
    if (wid) {
#pragma unroll
        for (int r = 0; r < 16; ++r) {
            const int tr = (r & 3) + 8 * (r >> 2) + 4 * g;
            P[(wid - 1) * 2048 + tr * 64 + lq]      = o0[r];
            P[(wid - 1) * 2048 + tr * 64 + 32 + lq] = o1[r];
        }
    }
    __syncthreads();
    if (!wid) {
        const int b = bh / Hn, hh = bh % Hn;
#pragma unroll
        for (int r = 0; r < 16; ++r) {
            const int tr = (r & 3) + 8 * (r >> 2) + 4 * g;
            float* base = heads + ((size_t)(b * Tn + (qbase + tr))) * Dn + hh * DHn;
            base[lq]      = o0[r] + P[tr * 64 + lq]
                          + P[2048 + tr * 64 + lq] + P[4096 + tr * 64 + lq];
            base[32 + lq] = o1[r] + P[tr * 64 + 32 + lq]
                          + P[2048 + tr * 64 + 32 + lq] + P[4096 + tr * 64 + 32 + lq];
        }
    }
}

extern "C" void kernel_launch(void* const* d_in, const int* in_sizes, int n_in,
                              void* d_out, int out_size, void* d_ws, size_t ws_size,
                              hipStream_t stream) {
    (void)in_sizes; (void)n_in; (void)out_size; (void)ws_size;
    const float* x  = (const float*)d_in[0];
    const float* Wq = (const float*)d_in[1];
    const float* bq = (const float*)d_in[2];
    const float* Wk = (const float*)d_in[3];
    const float* bk = (const float*)d_in[4];
    const float* Wv = (const float*)d_in[5];
    const float* bv = (const float*)d_in[6];
    // d_in[7] = attn_mask: structurally causal, handled in-kernel.

    float* heads = (float*)d_out;
    float* attn  = heads + (size_t)Bn * Tn * Dn;

    unsigned short* xbf  = (unsigned short*)d_ws;   // [NX] then [3][NW] weights
    unsigned short* qws  = xbf + NX + 3 * (size_t)NW;
    unsigned short* kws  = qws + NX;
    unsigned short* vtws = kws + NX;
    float* lsum = (float*)(vtws + NX);              // [BH][T]

    cvt_bf16<<<(NX + 3 * NW) / (256 * 8), 256, 0, stream>>>(x, Wq, Wk, Wv, xbf);
    proj_staged<<<dim3(32, 6, 3), 256, 0, stream>>>(xbf, xbf + NX, bq, bk, bv,
                                                    qws, kws, vtws);
    lsum_kernel<<<768, 256, 0, stream>>>(qws, kws, lsum);
    attn_main<<<1536, 256, 0, stream>>>(qws, kws, vtws, lsum, heads, attn);
}

// Round 13
// 170.957 us; speedup vs baseline: 1.2162x; 1.0208x over previous
//
#include <hip/hip_runtime.h>

typedef float f32x16 __attribute__((ext_vector_type(16)));
typedef float f32x4  __attribute__((ext_vector_type(4)));
typedef short s16x8  __attribute__((ext_vector_type(8)));
typedef short s16x4  __attribute__((ext_vector_type(4)));

constexpr int Bn = 2, Tn = 2048, Dn = 768, Hn = 12, DHn = 64;
constexpr int NX = Bn * Tn * Dn;   // 3,145,728
constexpr int NW = Dn * Dn;        // 589,824
constexpr float SC2f = 0.125f * 1.44269504088896f;  // (1/sqrt(64))*log2(e)

__device__ __forceinline__ unsigned short f2bf(float f) {
    union { float f; unsigned int i; } c; c.f = f;
    unsigned int u = c.i;
    u += 0x7fffu + ((u >> 16) & 1u);
    return (unsigned short)(u >> 16);
}
__device__ __forceinline__ unsigned int cvtpk(float lo, float hi) {
    unsigned int r;
    asm("v_cvt_pk_bf16_f32 %0, %1, %2" : "=v"(r) : "v"(lo), "v"(hi));
    return r;
}
__device__ __forceinline__ s16x8 comb(s16x4 lo, s16x4 hi) {
    s16x8 r;
    r[0]=lo[0]; r[1]=lo[1]; r[2]=lo[2]; r[3]=lo[3];
    r[4]=hi[0]; r[5]=hi[1]; r[6]=hi[2]; r[7]=hi[3];
    return r;
}
__device__ __forceinline__ void barrier_lgkm() {
    asm volatile("s_waitcnt lgkmcnt(0)" ::: "memory");
    __builtin_amdgcn_s_barrier();
    asm volatile("" ::: "memory");
}

// ---- f32 -> bf16 one-shot conversion of x, Wq, Wk, Wv into ws ----
__global__ __launch_bounds__(256) void cvt_bf16(
    const float* __restrict__ x,  const float* __restrict__ wq,
    const float* __restrict__ wk, const float* __restrict__ wv,
    unsigned short* __restrict__ out)
{
    const long i8 = ((long)blockIdx.x * 256 + threadIdx.x) * 8;
    const float* src;
    if (i8 < NX)               src = x  + i8;
    else if (i8 < NX + NW)     src = wq + (i8 - NX);
    else if (i8 < NX + 2*NW)   src = wk + (i8 - NX - 2l*NW + NW);
    else                       src = wv + (i8 - NX - 2l*NW);
    f32x4 a = *(const f32x4*)src;
    f32x4 b = *(const f32x4*)(src + 4);
    union { unsigned int u[4]; s16x8 v; } P;
    P.u[0] = cvtpk(a[0], a[1]); P.u[1] = cvtpk(a[2], a[3]);
    P.u[2] = cvtpk(b[0], b[1]); P.u[3] = cvtpk(b[2], b[3]);
    *(s16x8*)(out + i8) = P.v;
}

// ---- LDS-staged QKV projection: 128x128 tile, BK=32, double-buffered ----
__global__ __launch_bounds__(256) void proj_staged(
    const unsigned short* __restrict__ xbf,
    const unsigned short* __restrict__ wbf,   // [3][NW]
    const float* __restrict__ bq, const float* __restrict__ bk,
    const float* __restrict__ bv,
    unsigned short* __restrict__ qo, unsigned short* __restrict__ ko,
    unsigned short* __restrict__ vo)
{
    __shared__ unsigned short lA[2][128 * 40];
    __shared__ unsigned short lB[2][128 * 40];

    const int z = blockIdx.z;
    const bool vt = (z == 2);
    const unsigned short* W = wbf + (size_t)z * NW;
    const float* bias = (z == 0) ? bq : (z == 1) ? bk : bv;
    const int tid = threadIdx.x, lane = tid & 63, wid = tid >> 6;
    const int lq = lane & 31, g = lane >> 5;
    const int mb = vt ? blockIdx.y : blockIdx.x;
    const int nb = vt ? blockIdx.x : blockIdx.y;
    const unsigned short* Am = vt ? W : xbf;
    const unsigned short* Bm = vt ? xbf : W;

    const int srow = tid >> 2, sch = tid & 3;
    const unsigned short* ag0 = Am + (size_t)(mb * 128 +      srow) * Dn + sch * 8;
    const unsigned short* ag1 = Am + (size_t)(mb * 128 + 64 + srow) * Dn + sch * 8;
    const unsigned short* bg0 = Bm + (size_t)(nb * 128 +      srow) * Dn + sch * 8;
    const unsigned short* bg1 = Bm + (size_t)(nb * 128 + 64 + srow) * Dn + sch * 8;
    const int sd0 = srow * 40 + sch * 8;
    const int sd1 = (64 + srow) * 40 + sch * 8;

    f32x16 acc[2][2];
#pragma unroll
    for (int am = 0; am < 2; ++am)
#pragma unroll
        for (int bn = 0; bn < 2; ++bn)
#pragma unroll
            for (int i = 0; i < 16; ++i) acc[am][bn][i] = 0.f;

    {
        s16x8 a0 = *(const s16x8*)ag0, a1 = *(const s16x8*)ag1;
        s16x8 b0 = *(const s16x8*)bg0, b1 = *(const s16x8*)bg1;
        *(s16x8*)&lA[0][sd0] = a0; *(s16x8*)&lA[0][sd1] = a1;
        *(s16x8*)&lB[0][sd0] = b0; *(s16x8*)&lB[0][sd1] = b1;
    }
    const int ar = (wid & 1) * 64 + lq;
    const int br = (wid >> 1) * 64 + lq;

    for (int kt = 0; kt < 24; ++kt) {
        const int cur = kt & 1;
        s16x8 a0, a1, b0, b1;
        if (kt < 23) {
            a0 = *(const s16x8*)(ag0 + (kt + 1) * 32);
            a1 = *(const s16x8*)(ag1 + (kt + 1) * 32);
            b0 = *(const s16x8*)(bg0 + (kt + 1) * 32);
            b1 = *(const s16x8*)(bg1 + (kt + 1) * 32);
        }
        barrier_lgkm();
        s16x8 afr[2][2], bfr[2][2];
#pragma unroll
        for (int am = 0; am < 2; ++am)
#pragma unroll
            for (int kc = 0; kc < 2; ++kc)
                afr[am][kc] = *(const s16x8*)&lA[cur][(ar + am * 32) * 40 + (2 * kc + g) * 8];
#pragma unroll
        for (int bn = 0; bn < 2; ++bn)
#pragma unroll
            for (int kc = 0; kc < 2; ++kc)
                bfr[bn][kc] = *(const s16x8*)&lB[cur][(br + bn * 32) * 40 + (2 * kc + g) * 8];
#pragma unroll
        for (int kc = 0; kc < 2; ++kc)
#pragma unroll
            for (int am = 0; am < 2; ++am)
#pragma unroll
                for (int bn = 0; bn < 2; ++bn)
                    acc[am][bn] = __builtin_amdgcn_mfma_f32_32x32x16_bf16(
                        afr[am][kc], bfr[bn][kc], acc[am][bn], 0, 0, 0);
        if (kt < 23) {
            *(s16x8*)&lA[cur ^ 1][sd0] = a0; *(s16x8*)&lA[cur ^ 1][sd1] = a1;
            *(s16x8*)&lB[cur ^ 1][sd0] = b0; *(s16x8*)&lB[cur ^ 1][sd1] = b1;
        }
    }

    if (!vt) {
        unsigned short* out = (z == 0) ? qo : ko;
        const float scale = (z == 0) ? SC2f : 1.f;
#pragma unroll
        for (int bn = 0; bn < 2; ++bn) {
            const int e = nb * 128 + (wid >> 1) * 64 + bn * 32 + lq;
            const float bvl = bias[e];
            const int h = e >> 6, dh = e & 63;
#pragma unroll
            for (int am = 0; am < 2; ++am)
#pragma unroll
                for (int r = 0; r < 16; ++r) {
                    const int t = mb * 128 + (wid & 1) * 64 + am * 32 + ((r & 3) + 8 * (r >> 2) + 4 * g);
                    const int b = t >> 11, tl = t & (Tn - 1);
                    out[((size_t)(b * Hn + h) * Tn + tl) * DHn + dh] = f2bf((acc[am][bn][r] + bvl) * scale);
                }
        }
    } else {
#pragma unroll
        for (int am = 0; am < 2; ++am)
#pragma unroll
            for (int r = 0; r < 16; ++r) {
                const int e = mb * 128 + (wid & 1) * 64 + am * 32 + ((r & 3) + 8 * (r >> 2) + 4 * g);
                const float bvl = bias[e];
                const int h = e >> 6, dh = e & 63;
#pragma unroll
                for (int bn = 0; bn < 2; ++bn) {
                    const int t = nb * 128 + (wid >> 1) * 64 + bn * 32 + lq;
                    const int b = t >> 11, tl = t & (Tn - 1);
                    vo[((size_t)(b * Hn + h) * DHn + dh) * Tn + tl] = f2bf(acc[am][bn][r] + bvl);
                }
            }
    }
}

// ---- main attention, FULLY FUSED: block-local denominator prepass +
// panel-buffered row-contiguous NT writes ----
// Block = one 32-row strip (1536 blocks, longest-first per XCD), 4 waves
// = kt stride-4. Prepass: each wave sums exp2 over its kt subset (pure
// compute -> hides under other blocks' store drain), 512B LDS reduce.
// Main: P tiles -> 32x256 LDS panel (XOR-swizzled); per panel flush 32 rows
// as 1KB-contiguous NT stores. Causal zeros ride the panel. PV per-wave;
// O combined via panel overlay.
__global__ __launch_bounds__(256) void attn_main(
    const unsigned short* __restrict__ Q,   // [BH][T][Dh], pre-scaled
    const unsigned short* __restrict__ K,   // [BH][T][Dh]
    const unsigned short* __restrict__ Vt,  // [BH][Dh][T]
    float* __restrict__ heads,              // [B][T][H][Dh]
    float* __restrict__ attn)               // [BH][T][T]
{
    __shared__ float P[32 * 256];           // 32KB panel; O-combine overlay
    __shared__ float pls[4][32];

    const int tid = threadIdx.x, lane = tid & 63, wid = tid >> 6;
    const int lq = lane & 31, g = lane >> 5;
    // 1536 blocks: XCD k owns heads [3k,3k+3); longest strips first.
    const int n2 = ((int)blockIdx.x & 7) * 192 + ((int)blockIdx.x >> 3);
    const int bh = n2 >> 6;
    const int s  = 63 - (n2 & 63);
    const int qbase = s * 32;

    const unsigned short* Qb = Q  + ((size_t)bh * Tn + qbase) * DHn;
    const unsigned short* Kb = K  + (size_t)bh * Tn * DHn;
    const unsigned short* Vb = Vt + (size_t)bh * DHn * Tn;
    const int swz = (lq & 7) << 2;

    s16x8 qf[4];
#pragma unroll
    for (int c = 0; c < 4; ++c)
        qf[c] = *(const s16x8*)(Qb + lq * DHn + c * 16 + g * 8);

    // ---- prepass: block-local softmax denominator ----
    float ls = 0.f;
    for (int kt = wid; kt <= s; kt += 4) {
        const unsigned short* krow = Kb + (size_t)(kt * 32 + lq) * DHn + g * 8;
        f32x16 acc;
#pragma unroll
        for (int i = 0; i < 16; ++i) acc[i] = 0.f;
#pragma unroll
        for (int c = 0; c < 4; ++c)
            acc = __builtin_amdgcn_mfma_f32_32x32x16_bf16(
                *(const s16x8*)(krow + c * 16), qf[c], acc, 0, 0, 0);
        if (kt == s) {
#pragma unroll
            for (int r = 0; r < 16; ++r) {
                const int koff = (r & 3) + 8 * (r >> 2) + 4 * g;
                ls += (koff <= lq) ? exp2f(acc[r]) : 0.f;
            }
        } else {
#pragma unroll
            for (int r = 0; r < 16; ++r) ls += exp2f(acc[r]);
        }
    }
    ls += __shfl_xor(ls, 32);
    if (g == 0) pls[wid][lq] = ls;
    __syncthreads();
    const float rl = 1.f / (pls[0][lq] + pls[1][lq] + pls[2][lq] + pls[3][lq]);

    f32x16 o0, o1;
#pragma unroll
    for (int i = 0; i < 16; ++i) { o0[i] = 0.f; o1[i] = 0.f; }

    // ---- main loop: panels of 8 tiles ----
    for (int p = 0; p < 8; ++p) {
#pragma unroll
        for (int j = 0; j < 2; ++j) {
            const int kt = p * 8 + wid + 4 * j;
            const int slot = (kt & 7) * 32;
            if (kt <= s) {
                const unsigned short* krow = Kb + (size_t)(kt * 32 + lq) * DHn + g * 8;
                f32x16 acc;
#pragma unroll
                for (int i = 0; i < 16; ++i) acc[i] = 0.f;
#pragma unroll
                for (int c = 0; c < 4; ++c)
                    acc = __builtin_amdgcn_mfma_f32_32x32x16_bf16(
                        *(const s16x8*)(krow + c * 16), qf[c], acc, 0, 0, 0);
                const bool diag = (kt == s);
                float pv[16];
#pragma unroll
                for (int r = 0; r < 16; ++r) {
                    const int koff = (r & 3) + 8 * (r >> 2) + 4 * g;
                    float e = exp2f(acc[r]) * rl;
                    pv[r] = (diag && koff > lq) ? 0.f : e;
                }
                // P-tile into panel (row lq, swizzled cols)
#pragma unroll
                for (int a = 0; a < 4; ++a) {
                    f32x4 w;
                    w[0]=pv[4*a+0]; w[1]=pv[4*a+1]; w[2]=pv[4*a+2]; w[3]=pv[4*a+3];
                    *(f32x4*)&P[lq * 256 + slot + ((4 * g + 8 * a) ^ swz)] = w;
                }
                // PV: P (bf16) via cvt_pk; V^T fragments, matching k-bijection
                union { unsigned int uu[4]; s16x8 v; } P0, P1;
                P0.uu[0]=cvtpk(pv[0],pv[1]);   P0.uu[1]=cvtpk(pv[2],pv[3]);
                P0.uu[2]=cvtpk(pv[4],pv[5]);   P0.uu[3]=cvtpk(pv[6],pv[7]);
                P1.uu[0]=cvtpk(pv[8],pv[9]);   P1.uu[1]=cvtpk(pv[10],pv[11]);
                P1.uu[2]=cvtpk(pv[12],pv[13]); P1.uu[3]=cvtpk(pv[14],pv[15]);
                const unsigned short* vr0 = Vb + (size_t)lq * Tn + kt * 32;
                const unsigned short* vr1 = Vb + (size_t)(32 + lq) * Tn + kt * 32;
#pragma unroll
                for (int c2 = 0; c2 < 2; ++c2) {
                    const s16x8 pa = c2 ? P1.v : P0.v;
                    s16x4 lo0 = *(const s16x4*)(vr0 + c2 * 16 + 4 * g);
                    s16x4 hi0 = *(const s16x4*)(vr0 + c2 * 16 + 8 + 4 * g);
                    o0 = __builtin_amdgcn_mfma_f32_32x32x16_bf16(pa, comb(lo0, hi0), o0, 0, 0, 0);
                    s16x4 lo1 = *(const s16x4*)(vr1 + c2 * 16 + 4 * g);
                    s16x4 hi1 = *(const s16x4*)(vr1 + c2 * 16 + 8 + 4 * g);
                    o1 = __builtin_amdgcn_mfma_f32_32x32x16_bf16(pa, comb(lo1, hi1), o1, 0, 0, 0);
                }
            } else if (kt < 8 || kt - 8 <= s) {
                // first time this slot goes past the diagonal: zero it once
                f32x4 z; z[0]=0.f; z[1]=0.f; z[2]=0.f; z[3]=0.f;
#pragma unroll
                for (int a = 0; a < 4; ++a)
                    *(f32x4*)&P[lq * 256 + slot + ((4 * g + 8 * a) ^ swz)] = z;
            }
        }
        barrier_lgkm();
        // flush panel p: wave wid writes rows wid*8..wid*8+7, 1KB/row NT
#pragma unroll
        for (int j2 = 0; j2 < 8; ++j2) {
            const int row = wid * 8 + j2;
            f32x4 w = *(const f32x4*)&P[row * 256 + ((lane * 4) ^ ((row & 7) << 2))];
            __builtin_nontemporal_store(w,
                (f32x4*)(attn + ((size_t)bh * Tn + qbase + row) * Tn + p * 256 + lane * 4));
        }
        barrier_lgkm();
    }

    // ---- combine 4 waves' O via panel overlay; wave 0 writes heads ----
    if (wid) {
#pragma unroll
        for (int r = 0; r < 16; ++r) {
            const int tr = (r & 3) + 8 * (r >> 2) + 4 * g;
            P[(wid - 1) * 2048 + tr * 64 + lq]      = o0[r];
            P[(wid - 1) * 2048 + tr * 64 + 32 + lq] = o1[r];
        }
    }
    __syncthreads();
    if (!wid) {
        const int b = bh / Hn, hh = bh % Hn;
#pragma unroll
        for (int r = 0; r < 16; ++r) {
            const int tr = (r & 3) + 8 * (r >> 2) + 4 * g;
            float* base = heads + ((size_t)(b * Tn + (qbase + tr))) * Dn + hh * DHn;
            base[lq]      = o0[r] + P[tr * 64 + lq]
                          + P[2048 + tr * 64 + lq] + P[4096 + tr * 64 + lq];
            base[32 + lq] = o1[r] + P[tr * 64 + 32 + lq]
                          + P[2048 + tr * 64 + 32 + lq] + P[4096 + tr * 64 + 32 + lq];
        }
    }
}

extern "C" void kernel_launch(void* const* d_in, const int* in_sizes, int n_in,
                              void* d_out, int out_size, void* d_ws, size_t ws_size,
                              hipStream_t stream) {
    (void)in_sizes; (void)n_in; (void)out_size; (void)ws_size;
    const float* x  = (const float*)d_in[0];
    const float* Wq = (const float*)d_in[1];
    const float* bq = (const float*)d_in[2];
    const float* Wk = (const float*)d_in[3];
    const float* bk = (const float*)d_in[4];
    const float* Wv = (const float*)d_in[5];
    const float* bv = (const float*)d_in[6];
    // d_in[7] = attn_mask: structurally causal, handled in-kernel.

    float* heads = (float*)d_out;
    float* attn  = heads + (size_t)Bn * Tn * Dn;

    unsigned short* xbf  = (unsigned short*)d_ws;   // [NX] then [3][NW] weights
    unsigned short* qws  = xbf + NX + 3 * (size_t)NW;
    unsigned short* kws  = qws + NX;
    unsigned short* vtws = kws + NX;

    cvt_bf16<<<(NX + 3 * NW) / (256 * 8), 256, 0, stream>>>(x, Wq, Wk, Wv, xbf);
    proj_staged<<<dim3(32, 6, 3), 256, 0, stream>>>(xbf, xbf + NX, bq, bk, bv,
                                                    qws, kws, vtws);
    attn_main<<<1536, 256, 0, stream>>>(qws, kws, vtws, heads, attn);
}